// Round 20
// baseline (198.529 us; speedup 1.0000x reference)
//
#include <hip/hip_runtime.h>
#include <hip/hip_bf16.h>

typedef __bf16 bf16;
typedef __bf16 bf16x8 __attribute__((ext_vector_type(8)));
typedef __bf16 bf16x4 __attribute__((ext_vector_type(4)));
typedef float  f32x4  __attribute__((ext_vector_type(4)));
typedef float  f32x16 __attribute__((ext_vector_type(16)));

#define GLD_LDS(g, l)                                                        \
  __builtin_amdgcn_global_load_lds(                                          \
      (const __attribute__((address_space(1))) void*)(g),                    \
      (__attribute__((address_space(3))) void*)(l), 16, 0, 0)

#define SB()    __builtin_amdgcn_s_barrier()
#define WVM(n)  asm volatile("s_waitcnt vmcnt(" #n ")" ::: "memory")
#define PRIO1() __builtin_amdgcn_s_setprio(1)
#define PRIO0() __builtin_amdgcn_s_setprio(0)

// single TU-wide dynamic LDS symbol
extern __shared__ char lds[];

// ---------------------------------------------------------------------------
// GEMM2: R19 structure (persistent 256x256, 8-phase single-barrier, counted
// vmcnt ledger, verified swizzle/staging) with the MFMA core switched to
// v_mfma_f32_32x32x16_bf16 (ubench 2382 vs 2075 TF: +15% matrix-pipe
// efficiency; halves MFMA instruction count).
//  - LDS layout & staging UNCHANGED (linear gld_lds dest; granule g of row r
//    holds k-chunk g^(r&7), global source pre-swizzled — rule #21).
//  - 32x32 read addressing: lane l, slice ks in [0,4): row=l&31 (128B
//    stride), chunk q=2ks+(l>>5) -> byte col = (ks<<5|(l>>5)<<4)^((l&7)<<4);
//    XOR-decomposes into 4 LOOP-INVARIANT base pointers AK[ks]/BK[ks] per
//    operand + imm offsets (mi*4096, ni*4096, p*32768). Bank count = 8
//    accesses/bank = b128 minimum (conflict-free coset argument).
//  - MFMA frag layout (m74/m101-verified C/D): col=lane&31,
//    row=(reg&3)+8*(reg>>2)+4*(lane>>5); A row=lane&31 k=(lane>>5)*8+j,
//    B swap-symmetric (same arrangement as the verified 16x16 path).
//  - Ledger (verified): ph1 T+1.Ah1 | ph2 T+1.Bh0 | ph3 T+1.Bh1 | ph4
//    T+2.Ah0 +WVM2 | ph5..ph8 mirrored; peeled last pair drains WVM(0).
// ---------------------------------------------------------------------------
template <int EPI, int NP>
__global__ __launch_bounds__(512, 2)
void gemm256(const bf16* __restrict__ A, const bf16* __restrict__ B,
             bf16* __restrict__ Cb, float* __restrict__ Cf,
             const float* __restrict__ bias_p, int M) {
  constexpr int KP = 1024;
  constexpr int NT = KP / 64;            // 16 K-tiles
  bf16* ldsh = (bf16*)lds;
  const int tid  = threadIdx.x;
  const int lane = tid & 63, wave = tid >> 6;
  const int wm = wave >> 2, wn = wave & 3;       // 2 x 4 waves
  const int l31 = lane & 31, l7 = lane & 7, hi5 = lane >> 5;

  const int nwg = gridDim.x;
  const int bid = blockIdx.x;
  constexpr int gx = NP >> 8;
  const int nTiles = (M >> 8) * gx;
  const int rounds = nTiles / nwg;

  // staging source lane geometry (pre-swizzled k-chunk) — UNCHANGED
  const int srow = wave * 8 + (lane >> 3);
  const int scol = ((lane & 7) ^ (lane >> 3)) * 8;

  bf16* ldsA = ldsh + wave * 512;
  bf16* ldsB = ldsh + 32768 + wave * 512;
  const char* ldsc = (const char*)ldsh;

  // 4 loop-invariant read bases per operand (slice ks)
  const char* AK[4];
  const char* BK[4];
#pragma unroll
  for (int ks_ = 0; ks_ < 4; ++ks_) {
    const int cb = (((hi5 << 4) ^ (l7 << 4)) ^ (ks_ << 5));
    AK[ks_] = ldsc + wm * 16384 + l31 * 128 + cb;
    BK[ks_] = ldsc + 65536 + wn * 8192 + l31 * 128 + cb;
  }

  const float bias = (EPI == 1) ? bias_p[0] : 0.0f;

#define STG2(p0, p1, trel, base, off)                                        \
  do {                                                                       \
    GLD_LDS((p0) + (trel) * 64, (base) + (off));                             \
    GLD_LDS((p1) + (trel) * 64, (base) + (off) + 4096);                      \
  } while (0)

#define LDA32(mg, p)                                                         \
  do {                                                                       \
    _Pragma("unroll") for (int mi_ = 0; mi_ < 2; ++mi_)                      \
      _Pragma("unroll") for (int ks_ = 0; ks_ < 4; ++ks_)                    \
        af[mi_][ks_] = *(const bf16x8*)(AK[ks_] + (p) * 32768 +              \
                                        ((mg) * 2 + mi_) * 4096);            \
  } while (0)

#define LDB32(BG, np, p)                                                     \
  do {                                                                       \
    _Pragma("unroll") for (int ks_ = 0; ks_ < 4; ++ks_)                      \
      BG[ks_] = *(const bf16x8*)(BK[ks_] + (p) * 32768 + (np) * 4096);       \
  } while (0)

#define MMX(mg, BG, np)                                                      \
  do {                                                                       \
    _Pragma("unroll") for (int ks_ = 0; ks_ < 4; ++ks_)                      \
      _Pragma("unroll") for (int mi_ = 0; mi_ < 2; ++mi_)                    \
        acc[(mg) * 2 + mi_][np] = __builtin_amdgcn_mfma_f32_32x32x16_bf16(   \
            af[mi_][ks_], BG[ks_], acc[(mg) * 2 + mi_][np], 0, 0, 0);        \
  } while (0)

// SINGLE-BARRIER phase (R19-verified): reads/stage issue, MFMA consumes
// (in-wave lgkm deps), counted gate, one closing barrier.
#define PHASE(RDS, STAGE, MMC, GATE)                                         \
  do { RDS; STAGE; PRIO1(); MMC; PRIO0(); GATE; SB(); } while (0)

#define RDA(p) do { LDB32(bgA, 0, p); LDA32(0, p); } while (0)
#define RDB(p) do { LDB32(bgB, 1, p); } while (0)
#define RDC(p) do { LDA32(1, p); } while (0)

  auto mapTile = [&](int rd, int& tr, int& tc) {
    if (NP == 8192 && nwg == 256 && (M >> 8) == 32) {
      const int xcd = bid & 7, pos = bid >> 3;
      tr = (rd >> 1) * 16 + (xcd >> 1) * 4 + (pos >> 3);
      tc = (rd & 1) * 16 + (xcd & 1) * 8 + (pos & 7);
    } else {
      const int li = rd * nwg + bid;
      const int swz = (li & 7) * (nTiles >> 3) + (li >> 3);
      tr = li < nTiles ? swz / gx : 0; tc = li < nTiles ? swz % gx : 0;
    }
  };

  int tr, tc;
  mapTile(0, tr, tc);
  int row0 = tr << 8, col0 = tc << 8;

  const bf16* a0 = A + (size_t)(row0 + srow) * KP + scol;
  const bf16* a1 = a0 + (size_t)64 * KP;
  const bf16* a2 = a0 + (size_t)128 * KP;
  const bf16* a3 = a0 + (size_t)192 * KP;
  const bf16* b0 = B + (size_t)(col0 + srow) * KP + scol;
  const bf16* b1 = b0 + (size_t)64 * KP;
  const bf16* b2 = b0 + (size_t)128 * KP;
  const bf16* b3 = b0 + (size_t)192 * KP;

  STG2(a0, a1, 0, ldsA, 0);
  STG2(a2, a3, 0, ldsA, 8192);
  STG2(b0, b1, 0, ldsB, 0);
  STG2(b2, b3, 0, ldsB, 8192);
  STG2(a0, a1, 1, ldsA, 16384);

  for (int rd = 0; rd < rounds; ++rd) {
    if (rd == 0) { WVM(2); } else { WVM(63); }
    SB();

    f32x16 acc[4][2] = {};
    bf16x8 af[2][4];
    bf16x8 bgA[4], bgB[4];

#pragma unroll 1
    for (int it = 0; it < NT / 2 - 1; ++it) {
      PHASE(RDA(0), STG2(a2, a3, 1, ldsA, 24576), MMX(0, bgA, 0), );
      PHASE(RDB(0), STG2(b0, b1, 1, ldsB, 16384), MMX(0, bgB, 1), );
      PHASE(RDC(0), STG2(b2, b3, 1, ldsB, 24576), MMX(1, bgA, 0), );
      PHASE(      , STG2(a0, a1, 2, ldsA, 0),     MMX(1, bgB, 1), WVM(2));
      PHASE(RDA(1), STG2(a2, a3, 2, ldsA, 8192),  MMX(0, bgA, 0), );
      PHASE(RDB(1), STG2(b0, b1, 2, ldsB, 0),     MMX(0, bgB, 1), );
      PHASE(RDC(1), STG2(b2, b3, 2, ldsB, 8192),  MMX(1, bgA, 0), );
      PHASE(      , STG2(a0, a1, 3, ldsA, 16384), MMX(1, bgB, 1), WVM(2));
      a0 += 128; a1 += 128; a2 += 128; a3 += 128;
      b0 += 128; b1 += 128; b2 += 128; b3 += 128;
    }

    const bool hn = (rd + 1 < rounds);
    int ntr, ntc;
    mapTile(rd + 1, ntr, ntc);
    const int nrow0 = ntr << 8, ncol0 = ntc << 8;
    const bf16* na0 = A + (size_t)(nrow0 + srow) * KP + scol;
    const bf16* na1 = na0 + (size_t)64 * KP;
    const bf16* na2 = na0 + (size_t)128 * KP;
    const bf16* na3 = na0 + (size_t)192 * KP;
    const bf16* nb0 = B + (size_t)(ncol0 + srow) * KP + scol;
    const bf16* nb1 = nb0 + (size_t)64 * KP;
    const bf16* nb2 = nb0 + (size_t)128 * KP;
    const bf16* nb3 = nb0 + (size_t)192 * KP;

    PHASE(RDA(0), STG2(a2, a3, 1, ldsA, 24576), MMX(0, bgA, 0), );
    PHASE(RDB(0), STG2(b0, b1, 1, ldsB, 16384), MMX(0, bgB, 1), );
    PHASE(RDC(0), STG2(b2, b3, 1, ldsB, 24576), MMX(1, bgA, 0), );
    PHASE(      , if (hn) { STG2(na0, na1, 0, ldsA, 0); },    MMX(1, bgB, 1),
           if (hn) { WVM(2); } else { WVM(0); });
    PHASE(RDA(1), if (hn) { STG2(na2, na3, 0, ldsA, 8192); }, MMX(0, bgA, 0), );
    PHASE(RDB(1), if (hn) { STG2(nb0, nb1, 0, ldsB, 0); },    MMX(0, bgB, 1), );
    PHASE(RDC(1), if (hn) { STG2(nb2, nb3, 0, ldsB, 8192); }, MMX(1, bgA, 0), );
    PHASE(      , if (hn) { STG2(na0, na1, 1, ldsA, 16384); }, MMX(1, bgB, 1),
           if (hn) { WVM(2); } else { WVM(0); });

    // epilogue — 32x32 C/D layout (m74/m101-verified):
    // col = lane&31, row = (reg&3) + 8*(reg>>2) + 4*(lane>>5)
#pragma unroll
    for (int mi = 0; mi < 4; ++mi) {
#pragma unroll
      for (int ni = 0; ni < 2; ++ni) {
        const int rbase = row0 + wm * 128 + mi * 32 + 4 * hi5;
        const int c = col0 + wn * 64 + ni * 32 + l31;
#pragma unroll
        for (int reg = 0; reg < 16; ++reg) {
          const int r = rbase + (reg & 3) + 8 * (reg >> 2);
          if (EPI == 1)
            Cf[(size_t)r * NP + c] = acc[mi][ni][reg] + bias;
          else
            Cb[(size_t)r * NP + c] = (bf16)acc[mi][ni][reg];
        }
      }
    }

    a0 = na0; a1 = na1; a2 = na2; a3 = na3;
    b0 = nb0; b1 = nb1; b2 = nb2; b3 = nb3;
    row0 = nrow0; col0 = ncol0;
  }
#undef STG2
#undef LDA32
#undef LDB32
#undef MMX
#undef PHASE
#undef RDA
#undef RDB
#undef RDC
}

// ---------------------------------------------------------------------------
// GEMM1 kernel: R14-verified 128x128 kk-half kernel (absmax 0.5, 0 bank
// conflicts, 2 blocks/CU). 512 tiles -> all 256 CUs in ONE round. Unchanged.
// ---------------------------------------------------------------------------
template <int EPI, int NP>
__global__ __launch_bounds__(512, 4)
void gemm128k(const bf16* __restrict__ A, const bf16* __restrict__ B,
              bf16* __restrict__ Cb, float* __restrict__ Cf,
              const float* __restrict__ bias_p, int M) {
  constexpr int KP = 1024;
  constexpr int NT = KP / 64;
  const int tid  = threadIdx.x;
  const int lane = tid & 63, wave = tid >> 6;
  const int wm = wave >> 1, wn = wave & 1;      // 4 x 2 waves
  const int fr = lane & 15, fq = lane >> 4;
  const int laneb = (fr >> 1) * 128 + ((((fr & 1) * 4 + fq) ^ ((fr >> 1) & 7)) << 4);

  const int bid = blockIdx.x;
  constexpr int gx = NP >> 7;
  const int nTiles = (M >> 7) * gx;
  int tr, tc;
  {
    const int swz = (bid & 7) * (nTiles >> 3) + (bid >> 3);
    tr = swz / gx; tc = swz % gx;
  }
  const int row0 = tr << 7, col0 = tc << 7;

  const int gsw  = (tid & 7) ^ ((tid >> 3) & 7);
  const int srow = 2 * (tid >> 3) + (gsw >> 2);
  const int chnk = gsw & 3;
  const bf16* Agl = A + (size_t)(row0 + srow) * KP + chnk * 8;
  const bf16* Bgl = B + (size_t)(col0 + srow) * KP + chnk * 8;

#define STG1(gp, base_off, t, kk)                                            \
  GLD_LDS((gp) + (size_t)(t) * 64 + (kk) * 32,                               \
          lds + (base_off) + ((t) & 1) * 16384 + (kk) * 8192 + wave * 1024)

  const char* Ab = lds + wm * 2048 + laneb;
  const char* Bb = lds + 32768 + wn * 4096 + laneb;

  f32x4  acc[2][4] = {};
  bf16x8 af[2], bg[4];

#define LDA(kk, p)                                                           \
  do {                                                                       \
    _Pragma("unroll") for (int m_ = 0; m_ < 2; ++m_)                         \
      af[m_] = *(const bf16x8*)(Ab + (p) * 16384 + (kk) * 8192 + m_ * 1024); \
  } while (0)

#define LDBH(np, kk, p)                                                      \
  do {                                                                       \
    _Pragma("unroll") for (int n_ = 0; n_ < 2; ++n_)                         \
      bg[(np) * 2 + n_] = *(const bf16x8*)(Bb + (p) * 16384 + (kk) * 8192 +  \
                                           ((np) * 2 + n_) * 1024);          \
  } while (0)

#define MM(np)                                                               \
  do {                                                                       \
    _Pragma("unroll") for (int m_ = 0; m_ < 2; ++m_)                         \
      _Pragma("unroll") for (int n_ = 0; n_ < 2; ++n_)                       \
        acc[m_][(np) * 2 + n_] = __builtin_amdgcn_mfma_f32_16x16x32_bf16(    \
            af[m_], bg[(np) * 2 + n_], acc[m_][(np) * 2 + n_], 0, 0, 0);     \
  } while (0)

  STG1(Agl, 0, 0, 0); STG1(Bgl, 32768, 0, 0);
  STG1(Agl, 0, 0, 1); STG1(Bgl, 32768, 0, 1);
  WVM(2); SB();

  for (int T = 0; T < NT; ++T) {
    const int p = T & 1;
    const bool st = (T + 1 < NT);
    LDA(0, p); LDBH(0, 0, p);
    if (st) STG1(Agl, 0, T + 1, 0);
    PRIO1(); MM(0); PRIO0();
    LDBH(1, 0, p);
    if (st) STG1(Bgl, 32768, T + 1, 0);
    PRIO1(); MM(1); PRIO0();
    if (st) { WVM(2); } else { WVM(0); }
    SB();
    LDA(1, p); LDBH(0, 1, p);
    if (st) STG1(Agl, 0, T + 1, 1);
    PRIO1(); MM(0); PRIO0();
    LDBH(1, 1, p);
    if (st) STG1(Bgl, 32768, T + 1, 1);
    PRIO1(); MM(1); PRIO0();
    if (st) { WVM(2); } else { WVM(0); }
    SB();
  }

  const float bias = (EPI == 1) ? bias_p[0] : 0.0f;
#pragma unroll
  for (int m = 0; m < 2; ++m) {
#pragma unroll
    for (int n = 0; n < 4; ++n) {
      const int r = row0 + wm * 32 + m * 16 + fq * 4;
      const int c = col0 + wn * 64 + n * 16 + fr;
#pragma unroll
      for (int j = 0; j < 4; ++j) {
        if (EPI == 1)
          Cf[(size_t)(r + j) * NP + c] = acc[m][n][j] + bias;
        else
          Cb[(size_t)(r + j) * NP + c] = (bf16)acc[m][n][j];
      }
    }
  }
#undef STG1
#undef LDA
#undef LDBH
#undef MM
}

// ---------------------------------------------------------------------------
// prep: fused X->bf16 cast (blocks [0,8192)) + W transpose+cast
// ---------------------------------------------------------------------------
__global__ void prep(const float* __restrict__ X, bf16* __restrict__ Xb,
                     const float* __restrict__ W, bf16* __restrict__ Wt) {
  __shared__ float s[32][33];
  const int bid = blockIdx.x;
  if (bid < 8192) {
    const int i = bid * 256 + threadIdx.x;
    const float4 v = ((const float4*)X)[i];
    bf16x4 o;
    o[0] = (bf16)v.x; o[1] = (bf16)v.y; o[2] = (bf16)v.z; o[3] = (bf16)v.w;
    ((bf16x4*)Xb)[i] = o;
  } else {
    const int b2 = bid - 8192;
    const int tx = threadIdx.x & 31;
    const int ty = threadIdx.x >> 5;
    const int n0 = (b2 & 31) * 32;
    const int k0 = (b2 >> 5) * 32;
#pragma unroll
    for (int p = 0; p < 4; ++p)
      s[ty + p * 8][tx] = W[(size_t)(k0 + ty + p * 8) * 1024 + n0 + tx];
    __syncthreads();
#pragma unroll
    for (int p = 0; p < 4; ++p)
      Wt[(size_t)(n0 + ty + p * 8) * 1024 + k0 + tx] = (bf16)s[tx][ty + p * 8];
  }
}

extern "C" void kernel_launch(void* const* d_in, const int* in_sizes, int n_in,
                              void* d_out, int out_size, void* d_ws, size_t ws_size,
                              hipStream_t stream) {
  const float* X = (const float*)d_in[0];   // (8192, 1024)
  const float* W = (const float*)d_in[1];   // (1024, 1024)
  const float* b = (const float*)d_in[2];   // (1,)
  float* out = (float*)d_out;               // (8192, 8192)

  const int Nn = 8192;
  char* ws = (char*)d_ws;
  bf16* Xb  = (bf16*)(ws);
  bf16* XWb = (bf16*)(ws + (size_t)16 * 1024 * 1024);
  bf16* Wt  = (bf16*)(ws + (size_t)32 * 1024 * 1024);

  // X->bf16 and W->Wt (fused)
  prep<<<9216, 256, 0, stream>>>(X, Xb, W, Wt);
  // GEMM1: XW = Xb * Wt^T  (8192x1024) -> bf16; 512 blocks = all CUs, 1 round
  gemm128k<0, 1024><<<512, 512, 65536, stream>>>(Xb, Wt, XWb, nullptr, nullptr,
                                                 Nn);
  // GEMM2: out = XWb * Xb^T + b  (8192x8192) fp32; 256 persistent blocks x 4
  gemm256<1, 8192><<<256, 512, 131072, stream>>>(XWb, Xb, nullptr, out, b, Nn);
}

// Round 21
// 178.500 us; speedup vs baseline: 1.1122x; 1.1122x over previous
//
#include <hip/hip_runtime.h>
#include <hip/hip_bf16.h>

typedef __bf16 bf16;
typedef __bf16 bf16x8 __attribute__((ext_vector_type(8)));
typedef __bf16 bf16x4 __attribute__((ext_vector_type(4)));
typedef float  f32x4  __attribute__((ext_vector_type(4)));

#define GLD_LDS(g, l)                                                        \
  __builtin_amdgcn_global_load_lds(                                          \
      (const __attribute__((address_space(1))) void*)(g),                    \
      (__attribute__((address_space(3))) void*)(l), 16, 0, 0)

#define SB()    __builtin_amdgcn_s_barrier()
#define WVM(n)  asm volatile("s_waitcnt vmcnt(" #n ")" ::: "memory")
#define PRIO1() __builtin_amdgcn_s_setprio(1)
#define PRIO0() __builtin_amdgcn_s_setprio(0)

// single TU-wide dynamic LDS symbol (char: both kernels cast as needed)
extern __shared__ char lds[];

// ---------------------------------------------------------------------------
// GEMM2 kernel: R19-verified persistent 256x256 8-phase, SINGLE-BARRIER
// phases (best measured: total 178.7us, GEMM2 ~145us, MfmaUtil ~40%,
// 0 bank conflicts, absmax 0.5). Reverted verbatim after R20's 32x32
// experiment hit 1.26e7 bank conflicts (pre-committed tripwire).
// PHASE = {reads; stage; MFMA; gate; SB}; the single closing barrier plus
// per-wave counted WVM(2) carries all cross-wave hazards (ledger in R19).
// ---------------------------------------------------------------------------
template <int EPI, int NP>
__global__ __launch_bounds__(512, 2)
void gemm256(const bf16* __restrict__ A, const bf16* __restrict__ B,
             bf16* __restrict__ Cb, float* __restrict__ Cf,
             const float* __restrict__ bias_p, int M) {
  constexpr int KP = 1024;
  constexpr int NT = KP / 64;            // 16 K-tiles
  bf16* ldsh = (bf16*)lds;
  const int tid  = threadIdx.x;
  const int lane = tid & 63, wave = tid >> 6;
  const int wm = wave >> 2, wn = wave & 3;       // 2 x 4 waves
  const int fr = lane & 15, fq = lane >> 4;
  const int xm = (fr & 7) << 4;
  const int kx0 = (fq * 16) ^ xm;
  const int kx1 = (fq * 16 + 64) ^ xm;

  const int nwg = gridDim.x;
  const int bid = blockIdx.x;
  constexpr int gx = NP >> 8;
  const int nTiles = (M >> 8) * gx;
  const int rounds = nTiles / nwg;

  const int srow = wave * 8 + (lane >> 3);
  const int scol = ((lane & 7) ^ (lane >> 3)) * 8;

  bf16* ldsA = ldsh + wave * 512;
  bf16* ldsB = ldsh + 32768 + wave * 512;
  const char* ldsc = (const char*)ldsh;
  const char* Ab0 = ldsc + wm * 16384 + fr * 128 + kx0;
  const char* Ab1 = ldsc + wm * 16384 + fr * 128 + kx1;
  const char* Bb0 = ldsc + 65536 + wn * 8192 + fr * 128 + kx0;
  const char* Bb1 = ldsc + 65536 + wn * 8192 + fr * 128 + kx1;

  const float bias = (EPI == 1) ? bias_p[0] : 0.0f;

#define STG2(p0, p1, trel, base, off)                                        \
  do {                                                                       \
    GLD_LDS((p0) + (trel) * 64, (base) + (off));                             \
    GLD_LDS((p1) + (trel) * 64, (base) + (off) + 4096);                      \
  } while (0)

#define LDA4(mg, kk, p)                                                      \
  do {                                                                       \
    _Pragma("unroll") for (int m_ = 0; m_ < 4; ++m_)                         \
      af[m_][kk] = *(const bf16x8*)(Ab##kk + (p) * 32768 +                   \
                                    ((mg) * 4 + m_) * 2048);                 \
  } while (0)

#define LDB2(np, kk, p)                                                      \
  do {                                                                       \
    _Pragma("unroll") for (int n_ = 0; n_ < 2; ++n_)                         \
      bg[(np) * 2 + n_][kk] = *(const bf16x8*)(Bb##kk + (p) * 32768 +        \
                                               ((np) * 2 + n_) * 2048);      \
  } while (0)

#define MM(mg, np)                                                           \
  do {                                                                       \
    _Pragma("unroll") for (int kk_ = 0; kk_ < 2; ++kk_)                      \
      _Pragma("unroll") for (int m_ = 0; m_ < 4; ++m_)                       \
        _Pragma("unroll") for (int n_ = 0; n_ < 2; ++n_)                     \
          acc[(mg) * 4 + m_][(np) * 2 + n_] =                                \
              __builtin_amdgcn_mfma_f32_16x16x32_bf16(                       \
                  af[m_][kk_], bg[(np) * 2 + n_][kk_],                       \
                  acc[(mg) * 4 + m_][(np) * 2 + n_], 0, 0, 0);               \
  } while (0)

// SINGLE-BARRIER phase: reads/stage issue, MFMA consumes (in-wave deps),
// counted gate, one closing barrier.
#define PHASE(RDS, STAGE, MMC, GATE)                                         \
  do { RDS; STAGE; PRIO1(); MMC; PRIO0(); GATE; SB(); } while (0)

#define RD1 do { LDB2(0,0,0); LDA4(0,0,0); LDB2(0,1,0); LDA4(0,1,0); } while(0)
#define RD2 do { LDB2(1,0,0); LDB2(1,1,0); } while(0)
#define RD3 do { LDA4(1,0,0); LDA4(1,1,0); } while(0)
#define RD5 do { LDB2(0,0,1); LDA4(0,0,1); LDB2(0,1,1); LDA4(0,1,1); } while(0)
#define RD6 do { LDB2(1,0,1); LDB2(1,1,1); } while(0)
#define RD7 do { LDA4(1,0,1); LDA4(1,1,1); } while(0)

  auto mapTile = [&](int rd, int& tr, int& tc) {
    if (NP == 8192 && nwg == 256 && (M >> 8) == 32) {
      const int xcd = bid & 7, pos = bid >> 3;
      tr = (rd >> 1) * 16 + (xcd >> 1) * 4 + (pos >> 3);
      tc = (rd & 1) * 16 + (xcd & 1) * 8 + (pos & 7);
    } else {
      const int li = rd * nwg + bid;
      const int swz = (li & 7) * (nTiles >> 3) + (li >> 3);
      tr = li < nTiles ? swz / gx : 0; tc = li < nTiles ? swz % gx : 0;
    }
  };

  int tr, tc;
  mapTile(0, tr, tc);
  int row0 = tr << 8, col0 = tc << 8;

  const bf16* a0 = A + (size_t)(row0 + srow) * KP + scol;
  const bf16* a1 = a0 + (size_t)64 * KP;
  const bf16* a2 = a0 + (size_t)128 * KP;
  const bf16* a3 = a0 + (size_t)192 * KP;
  const bf16* b0 = B + (size_t)(col0 + srow) * KP + scol;
  const bf16* b1 = b0 + (size_t)64 * KP;
  const bf16* b2 = b0 + (size_t)128 * KP;
  const bf16* b3 = b0 + (size_t)192 * KP;

  STG2(a0, a1, 0, ldsA, 0);
  STG2(a2, a3, 0, ldsA, 8192);
  STG2(b0, b1, 0, ldsB, 0);
  STG2(b2, b3, 0, ldsB, 8192);
  STG2(a0, a1, 1, ldsA, 16384);

  for (int rd = 0; rd < rounds; ++rd) {
    if (rd == 0) { WVM(2); } else { WVM(63); }
    SB();

    f32x4  acc[8][4] = {};
    bf16x8 af[4][2];
    bf16x8 bg[4][2];

#pragma unroll 1
    for (int it = 0; it < NT / 2 - 1; ++it) {
      PHASE(RD1, STG2(a2, a3, 1, ldsA, 24576), MM(0, 0), );
      PHASE(RD2, STG2(b0, b1, 1, ldsB, 16384), MM(0, 1), );
      PHASE(RD3, STG2(b2, b3, 1, ldsB, 24576), MM(1, 0), );
      PHASE(   , STG2(a0, a1, 2, ldsA, 0),     MM(1, 1), WVM(2));
      PHASE(RD5, STG2(a2, a3, 2, ldsA, 8192),  MM(0, 0), );
      PHASE(RD6, STG2(b0, b1, 2, ldsB, 0),     MM(0, 1), );
      PHASE(RD7, STG2(b2, b3, 2, ldsB, 8192),  MM(1, 0), );
      PHASE(   , STG2(a0, a1, 3, ldsA, 16384), MM(1, 1), WVM(2));
      a0 += 128; a1 += 128; a2 += 128; a3 += 128;
      b0 += 128; b1 += 128; b2 += 128; b3 += 128;
    }

    const bool hn = (rd + 1 < rounds);
    int ntr, ntc;
    mapTile(rd + 1, ntr, ntc);
    const int nrow0 = ntr << 8, ncol0 = ntc << 8;
    const bf16* na0 = A + (size_t)(nrow0 + srow) * KP + scol;
    const bf16* na1 = na0 + (size_t)64 * KP;
    const bf16* na2 = na0 + (size_t)128 * KP;
    const bf16* na3 = na0 + (size_t)192 * KP;
    const bf16* nb0 = B + (size_t)(ncol0 + srow) * KP + scol;
    const bf16* nb1 = nb0 + (size_t)64 * KP;
    const bf16* nb2 = nb0 + (size_t)128 * KP;
    const bf16* nb3 = nb0 + (size_t)192 * KP;

    PHASE(RD1, STG2(a2, a3, 1, ldsA, 24576), MM(0, 0), );
    PHASE(RD2, STG2(b0, b1, 1, ldsB, 16384), MM(0, 1), );
    PHASE(RD3, STG2(b2, b3, 1, ldsB, 24576), MM(1, 0), );
    PHASE(   , if (hn) { STG2(na0, na1, 0, ldsA, 0); },    MM(1, 1),
           if (hn) { WVM(2); } else { WVM(0); });
    PHASE(RD5, if (hn) { STG2(na2, na3, 0, ldsA, 8192); }, MM(0, 0), );
    PHASE(RD6, if (hn) { STG2(nb0, nb1, 0, ldsB, 0); },    MM(0, 1), );
    PHASE(RD7, if (hn) { STG2(nb2, nb3, 0, ldsB, 8192); }, MM(1, 0), );
    PHASE(   , if (hn) { STG2(na0, na1, 1, ldsA, 16384); }, MM(1, 1),
           if (hn) { WVM(2); } else { WVM(0); });

    // epilogue — C/D layout (verified): col = lane&15, row = (lane>>4)*4 + j
#pragma unroll
    for (int m = 0; m < 8; ++m) {
#pragma unroll
      for (int n = 0; n < 4; ++n) {
        const int r = row0 + wm * 128 + m * 16 + fq * 4;
        const int c = col0 + wn * 64 + n * 16 + fr;
#pragma unroll
        for (int j = 0; j < 4; ++j) {
          if (EPI == 1)
            Cf[(size_t)(r + j) * NP + c] = acc[m][n][j] + bias;
          else
            Cb[(size_t)(r + j) * NP + c] = (bf16)acc[m][n][j];
        }
      }
    }

    a0 = na0; a1 = na1; a2 = na2; a3 = na3;
    b0 = nb0; b1 = nb1; b2 = nb2; b3 = nb3;
    row0 = nrow0; col0 = ncol0;
  }
#undef STG2
#undef LDA4
#undef LDB2
#undef MM
#undef PHASE
#undef RD1
#undef RD2
#undef RD3
#undef RD5
#undef RD6
#undef RD7
}

// ---------------------------------------------------------------------------
// GEMM1 kernel: R14-verified 128x128 kk-half kernel (absmax 0.5, 0 bank
// conflicts, 2 blocks/CU). 512 tiles -> all 256 CUs in ONE round.
// ---------------------------------------------------------------------------
template <int EPI, int NP>
__global__ __launch_bounds__(512, 4)
void gemm128k(const bf16* __restrict__ A, const bf16* __restrict__ B,
              bf16* __restrict__ Cb, float* __restrict__ Cf,
              const float* __restrict__ bias_p, int M) {
  constexpr int KP = 1024;
  constexpr int NT = KP / 64;
  const int tid  = threadIdx.x;
  const int lane = tid & 63, wave = tid >> 6;
  const int wm = wave >> 1, wn = wave & 1;      // 4 x 2 waves
  const int fr = lane & 15, fq = lane >> 4;
  const int laneb = (fr >> 1) * 128 + ((((fr & 1) * 4 + fq) ^ ((fr >> 1) & 7)) << 4);

  const int bid = blockIdx.x;
  constexpr int gx = NP >> 7;
  const int nTiles = (M >> 7) * gx;
  int tr, tc;
  {
    const int swz = (bid & 7) * (nTiles >> 3) + (bid >> 3);
    tr = swz / gx; tc = swz % gx;
  }
  const int row0 = tr << 7, col0 = tc << 7;

  const int gsw  = (tid & 7) ^ ((tid >> 3) & 7);
  const int srow = 2 * (tid >> 3) + (gsw >> 2);
  const int chnk = gsw & 3;
  const bf16* Agl = A + (size_t)(row0 + srow) * KP + chnk * 8;
  const bf16* Bgl = B + (size_t)(col0 + srow) * KP + chnk * 8;

#define STG1(gp, base_off, t, kk)                                            \
  GLD_LDS((gp) + (size_t)(t) * 64 + (kk) * 32,                               \
          lds + (base_off) + ((t) & 1) * 16384 + (kk) * 8192 + wave * 1024)

  const char* Ab = lds + wm * 2048 + laneb;
  const char* Bb = lds + 32768 + wn * 4096 + laneb;

  f32x4  acc[2][4] = {};
  bf16x8 af[2], bg[4];

#define LDA(kk, p)                                                           \
  do {                                                                       \
    _Pragma("unroll") for (int m_ = 0; m_ < 2; ++m_)                         \
      af[m_] = *(const bf16x8*)(Ab + (p) * 16384 + (kk) * 8192 + m_ * 1024); \
  } while (0)

#define LDBH(np, kk, p)                                                      \
  do {                                                                       \
    _Pragma("unroll") for (int n_ = 0; n_ < 2; ++n_)                         \
      bg[(np) * 2 + n_] = *(const bf16x8*)(Bb + (p) * 16384 + (kk) * 8192 +  \
                                           ((np) * 2 + n_) * 1024);          \
  } while (0)

#define MM(np)                                                               \
  do {                                                                       \
    _Pragma("unroll") for (int m_ = 0; m_ < 2; ++m_)                         \
      _Pragma("unroll") for (int n_ = 0; n_ < 2; ++n_)                       \
        acc[m_][(np) * 2 + n_] = __builtin_amdgcn_mfma_f32_16x16x32_bf16(    \
            af[m_], bg[(np) * 2 + n_], acc[m_][(np) * 2 + n_], 0, 0, 0);     \
  } while (0)

  STG1(Agl, 0, 0, 0); STG1(Bgl, 32768, 0, 0);
  STG1(Agl, 0, 0, 1); STG1(Bgl, 32768, 0, 1);
  WVM(2); SB();

  for (int T = 0; T < NT; ++T) {
    const int p = T & 1;
    const bool st = (T + 1 < NT);
    LDA(0, p); LDBH(0, 0, p);
    if (st) STG1(Agl, 0, T + 1, 0);
    PRIO1(); MM(0); PRIO0();
    LDBH(1, 0, p);
    if (st) STG1(Bgl, 32768, T + 1, 0);
    PRIO1(); MM(1); PRIO0();
    if (st) { WVM(2); } else { WVM(0); }
    SB();
    LDA(1, p); LDBH(0, 1, p);
    if (st) STG1(Agl, 0, T + 1, 1);
    PRIO1(); MM(0); PRIO0();
    LDBH(1, 1, p);
    if (st) STG1(Bgl, 32768, T + 1, 1);
    PRIO1(); MM(1); PRIO0();
    if (st) { WVM(2); } else { WVM(0); }
    SB();
  }

  const float bias = (EPI == 1) ? bias_p[0] : 0.0f;
#pragma unroll
  for (int m = 0; m < 2; ++m) {
#pragma unroll
    for (int n = 0; n < 4; ++n) {
      const int r = row0 + wm * 32 + m * 16 + fq * 4;
      const int c = col0 + wn * 64 + n * 16 + fr;
#pragma unroll
      for (int j = 0; j < 4; ++j) {
        if (EPI == 1)
          Cf[(size_t)(r + j) * NP + c] = acc[m][n][j] + bias;
        else
          Cb[(size_t)(r + j) * NP + c] = (bf16)acc[m][n][j];
      }
    }
  }
#undef STG1
#undef LDA
#undef LDBH
#undef MM
}

// ---------------------------------------------------------------------------
// prep: fused X->bf16 cast (blocks [0,8192)) + W transpose+cast
// ---------------------------------------------------------------------------
__global__ void prep(const float* __restrict__ X, bf16* __restrict__ Xb,
                     const float* __restrict__ W, bf16* __restrict__ Wt) {
  __shared__ float s[32][33];
  const int bid = blockIdx.x;
  if (bid < 8192) {
    const int i = bid * 256 + threadIdx.x;
    const float4 v = ((const float4*)X)[i];
    bf16x4 o;
    o[0] = (bf16)v.x; o[1] = (bf16)v.y; o[2] = (bf16)v.z; o[3] = (bf16)v.w;
    ((bf16x4*)Xb)[i] = o;
  } else {
    const int b2 = bid - 8192;
    const int tx = threadIdx.x & 31;
    const int ty = threadIdx.x >> 5;
    const int n0 = (b2 & 31) * 32;
    const int k0 = (b2 >> 5) * 32;
#pragma unroll
    for (int p = 0; p < 4; ++p)
      s[ty + p * 8][tx] = W[(size_t)(k0 + ty + p * 8) * 1024 + n0 + tx];
    __syncthreads();
#pragma unroll
    for (int p = 0; p < 4; ++p)
      Wt[(size_t)(n0 + ty + p * 8) * 1024 + k0 + tx] = (bf16)s[tx][ty + p * 8];
  }
}

extern "C" void kernel_launch(void* const* d_in, const int* in_sizes, int n_in,
                              void* d_out, int out_size, void* d_ws, size_t ws_size,
                              hipStream_t stream) {
  const float* X = (const float*)d_in[0];   // (8192, 1024)
  const float* W = (const float*)d_in[1];   // (1024, 1024)
  const float* b = (const float*)d_in[2];   // (1,)
  float* out = (float*)d_out;               // (8192, 8192)

  const int Nn = 8192;
  char* ws = (char*)d_ws;
  bf16* Xb  = (bf16*)(ws);
  bf16* XWb = (bf16*)(ws + (size_t)16 * 1024 * 1024);
  bf16* Wt  = (bf16*)(ws + (size_t)32 * 1024 * 1024);

  // X->bf16 and W->Wt (fused)
  prep<<<9216, 256, 0, stream>>>(X, Xb, W, Wt);
  // GEMM1: XW = Xb * Wt^T  (8192x1024) -> bf16; 512 blocks = all CUs, 1 round
  gemm128k<0, 1024><<<512, 512, 65536, stream>>>(Xb, Wt, XWb, nullptr, nullptr,
                                                 Nn);
  // GEMM2: out = XWb * Xb^T + b  (8192x8192) fp32; 256 persistent blocks x 4
  gemm256<1, 8192><<<256, 512, 131072, stream>>>(XWb, Xb, nullptr, out, b, Nn);
}